// Round 11
// baseline (675.145 us; speedup 1.0000x reference)
//
#include <hip/hip_runtime.h>
#include <hip/hip_bf16.h>
#include <hip/hip_cooperative_groups.h>

namespace cg = cooperative_groups;

// ---------------------------------------------------------------------------
// GNN layer (R11): 5 dispatches, bf16 attention tables.
//   1. rowproj_bf16: hproj16 = bf16(hidden @ Ws^T)
//   2. k_ct:         ct16[rel*8+b] = bf16(rela@Wr^T + rela[q_rel[b]]@Wqr^T+b)
//   3. k_csr (COOPERATIVE, 512 blocks): zero deg -> count+rank -> chunk
//      partials -> block0 scan -> rowptr -> key   (replaces 6 dispatches)
//   4. k_agg: per-node wave, 2 edges/wave, gathers hp/cv in bf16 (128 B) and
//      hd/rl in fp32; zero feature atomics; one 256 B store per node (d_out)
//   5. rowproj64: out = agg @ Wh^T in place on d_out
// R10 evidence: k_agg mixed-bound at 3.6 TB/s effective (FETCH 276 MB, VALU
// 65%); ~200 us unaccounted across 10 dispatches -> fuse + shrink bytes.
// ---------------------------------------------------------------------------

__device__ __forceinline__ unsigned short f2bf(float f) {
    unsigned int u = __float_as_uint(f);
    u += 0x7FFF + ((u >> 16) & 1);          // round-to-nearest-even
    return (unsigned short)(u >> 16);
}

// dst[r][a] = sum_k src[r][k] * W[a][k];  fp32 in/out, used in-place for the
// final projection (rows staged in LDS before overwrite).
__global__ __launch_bounds__(256) void rowproj64(const float* src,
                                                 const float* __restrict__ W,
                                                 float* dst, int nrows) {
    __shared__ float Wt[64][65];
    __shared__ float4 Sl[64][16];
    int tid = threadIdx.x;
    for (int i = tid; i < 4096; i += 256) Wt[i & 63][i >> 6] = W[i];
    long r0 = (long)blockIdx.x * 64;
    const float4* src4 = (const float4*)(src + r0 * 64);
    float4* s4 = (float4*)Sl;
    for (int i = tid; i < 1024; i += 256) s4[i] = src4[i];
    __syncthreads();
    int c = tid & 63;
    int rbase = (tid >> 6) * 16;
    float w[64];
#pragma unroll
    for (int k = 0; k < 64; ++k) w[k] = Wt[k][c];
#pragma unroll
    for (int r = 0; r < 16; ++r) {
        float a0 = 0.f, a1 = 0.f, a2 = 0.f, a3 = 0.f;
#pragma unroll
        for (int k4 = 0; k4 < 16; ++k4) {
            float4 s = Sl[rbase + r][k4];
            a0 += s.x * w[4 * k4 + 0];
            a1 += s.y * w[4 * k4 + 1];
            a2 += s.z * w[4 * k4 + 2];
            a3 += s.w * w[4 * k4 + 3];
        }
        dst[(r0 + rbase + r) * 64 + c] = (a0 + a1) + (a2 + a3);
    }
}

// Same projection, bf16 output (hproj table).
__global__ __launch_bounds__(256) void rowproj_bf16(const float* __restrict__ src,
                                                    const float* __restrict__ W,
                                                    unsigned short* __restrict__ dst,
                                                    int nrows) {
    __shared__ float Wt[64][65];
    __shared__ float4 Sl[64][16];
    int tid = threadIdx.x;
    for (int i = tid; i < 4096; i += 256) Wt[i & 63][i >> 6] = W[i];
    long r0 = (long)blockIdx.x * 64;
    const float4* src4 = (const float4*)(src + r0 * 64);
    float4* s4 = (float4*)Sl;
    for (int i = tid; i < 1024; i += 256) s4[i] = src4[i];
    __syncthreads();
    int c = tid & 63;
    int rbase = (tid >> 6) * 16;
    float w[64];
#pragma unroll
    for (int k = 0; k < 64; ++k) w[k] = Wt[k][c];
#pragma unroll
    for (int r = 0; r < 16; ++r) {
        float a0 = 0.f, a1 = 0.f, a2 = 0.f, a3 = 0.f;
#pragma unroll
        for (int k4 = 0; k4 < 16; ++k4) {
            float4 s = Sl[rbase + r][k4];
            a0 += s.x * w[4 * k4 + 0];
            a1 += s.y * w[4 * k4 + 1];
            a2 += s.z * w[4 * k4 + 2];
            a3 += s.w * w[4 * k4 + 3];
        }
        dst[(r0 + rbase + r) * 64 + c] = f2bf((a0 + a1) + (a2 + a3));
    }
}

// ct16[rel*8+b][a] = bf16((rela[rel]@Wr^T)[a] + (rela[q_rel[b]]@Wqr^T)[a] + bqr[a])
__global__ void k_ct(const float* __restrict__ rela,
                     const int* __restrict__ q_rel,
                     const float* __restrict__ Wr,
                     const float* __restrict__ Wqr,
                     const float* __restrict__ bqr,
                     unsigned short* __restrict__ ct, int B) {
    int rel = blockIdx.x, a = threadIdx.x;
    __shared__ float hr[64];
    __shared__ float hq[8][64];
    hr[a] = rela[(size_t)rel * 64 + a];
    for (int b = 0; b < B; ++b) hq[b][a] = rela[(size_t)q_rel[b] * 64 + a];
    __syncthreads();
    float accr = 0.f;
#pragma unroll
    for (int k = 0; k < 64; ++k) accr += hr[k] * Wr[a * 64 + k];
    for (int b = 0; b < B; ++b) {
        float acc = bqr[a];
#pragma unroll
        for (int k = 0; k < 64; ++k) acc += hq[b][k] * Wqr[a * 64 + k];
        ct[((size_t)rel * 8 + b) * 64 + a] = f2bf(accr + acc);
    }
}

// ---- COOPERATIVE CSR build + key scatter (one dispatch) --------------------
// 512 blocks x 256 threads (co-resident at 2 blocks/CU). Phases separated by
// grid.sync(): zero deg | count+rank | 512-chunk partials | block0 scans 512
// partials | per-chunk rowptr | key scatter.
__global__ __launch_bounds__(256, 2) void k_csr(
    const int* __restrict__ edges, int E, int N,
    int* __restrict__ deg, int* __restrict__ rank,
    int* __restrict__ partial, int* __restrict__ poffs,
    int* __restrict__ rowptr, unsigned int* __restrict__ key) {
    cg::grid_group grid = cg::this_grid();
    __shared__ int smem[1024];
    int t = threadIdx.x;
    int b = blockIdx.x;
    int gid = b * 256 + t;
    const int GSTRIDE = 512 * 256;
    int nchunk = (N + 511) >> 9;            // 512-element chunks

    // phase 0: zero deg
    for (int i = gid; i < N; i += GSTRIDE) deg[i] = 0;
    grid.sync();

    // phase 1: count + rank
    for (int e = gid; e < E; e += GSTRIDE)
        rank[e] = atomicAdd(&deg[edges[(size_t)e * 6 + 5]], 1);
    grid.sync();

    // phase 2: per-chunk partial sums (chunk = 512 deg entries)
    if (b < nchunk) {
        int c0 = b << 9;
        int v = 0;
        int i0 = c0 + t;       if (i0 < N) v = deg[i0];
        int i1 = c0 + t + 256; if (i1 < N) v += deg[i1];
        smem[t] = v;
        __syncthreads();
        for (int o = 128; o; o >>= 1) {
            if (t < o) smem[t] += smem[t + o];
            __syncthreads();
        }
        if (t == 0) partial[b] = smem[0];
    } else if (t == 0) {
        partial[b] = 0;
    }
    grid.sync();

    // phase 3: block 0 exclusive-scans the 512 partials -> poffs
    if (b == 0) {
        int* A = smem;
        int* Bb = smem + 512;
        int o0 = partial[t], o1 = partial[t + 256];
        A[t] = o0; A[t + 256] = o1;
        __syncthreads();
        for (int o = 1; o < 512; o <<= 1) {
            Bb[t] = A[t] + (t >= o ? A[t - o] : 0);
            int i2 = t + 256;
            Bb[i2] = A[i2] + (i2 >= o ? A[i2 - o] : 0);
            __syncthreads();
            int* tmp = A; A = Bb; Bb = tmp;
        }
        poffs[t] = A[t] - o0;
        poffs[t + 256] = A[t + 256] - o1;
    }
    grid.sync();

    // phase 4: per-chunk rowptr (pair-per-thread + 256-entry LDS scan)
    if (b < nchunk) {
        int c0 = b << 9;
        int i0 = c0 + 2 * t, i1 = i0 + 1;
        int d0 = (i0 < N) ? deg[i0] : 0;
        int d1 = (i1 < N) ? deg[i1] : 0;
        int ps = d0 + d1;
        int* A = smem;
        int* Bb = smem + 256;
        A[t] = ps;
        __syncthreads();
        for (int o = 1; o < 256; o <<= 1) {
            Bb[t] = A[t] + (t >= o ? A[t - o] : 0);
            __syncthreads();
            int* tmp = A; A = Bb; Bb = tmp;
        }
        int base = poffs[b] + A[t] - ps;    // exclusive within chunk
        if (i0 < N) rowptr[i0] = base;
        if (i1 < N) rowptr[i1] = base + d0;
    }
    if (gid == 0) rowptr[N] = E;
    grid.sync();

    // phase 5: key scatter (atomic-free: pos = rowptr[obj] + rank[e])
    for (int e = gid; e < E; e += GSTRIDE) {
        const int* ed = edges + (size_t)e * 6;
        int2 p0 = *(const int2*)(ed);       // {r_idx, 0}
        int2 p1 = *(const int2*)(ed + 2);   // {rel, 0}
        int2 p2 = *(const int2*)(ed + 4);   // {sub, obj}
        int pos = rowptr[p2.y] + rank[e];
        key[pos] = (unsigned int)p2.x | ((unsigned int)(p1.x * 8 + p0.x) << 18);
    }
}

// ---- FUSED alpha + aggregation, 2 edges per wave ---------------------------
// Lanes 0-31 = edge j, 32-63 = edge j+1; lane owns features {2li,2li+1}.
// hp/cv gathered as packed bf16 (4 B/lane = 128 B/row); hd/rl fp32.
__global__ __launch_bounds__(256) void k_agg(
    const int* __restrict__ rowptr,
    const unsigned int* __restrict__ key,
    const unsigned short* __restrict__ hproj16,
    const unsigned short* __restrict__ ct16,
    const float* __restrict__ hidden,
    const float* __restrict__ rela,
    const float* __restrict__ wa,
    const float* __restrict__ wab_p,
    float* __restrict__ agg, int N) {
    int lane = threadIdx.x & 63;
    int half = lane >> 5;
    int li   = lane & 31;
    int w = (int)((blockIdx.x * blockDim.x + threadIdx.x) >> 6);
    if (w >= N) return;
    int n = __builtin_amdgcn_readfirstlane(w);
    int s = rowptr[n], e = rowptr[n + 1];
    const unsigned int* hp2 = (const unsigned int*)hproj16;  // 32 uints/row
    const unsigned int* ct2 = (const unsigned int*)ct16;
    const float2* hidden2 = (const float2*)hidden;
    const float2* rela2   = (const float2*)rela;
    float2 wav = ((const float2*)wa)[li];
    float wab = wab_p[0];
    float2 acc = {0.f, 0.f};

    if (s < e) {
        int j1c = min(s + 1, e - 1);
        unsigned int ka = key[s], kb = key[j1c];
        unsigned int kk = half ? kb : ka;
        float vld = (half == 0 || s + 1 < e) ? 1.f : 0.f;
        int sub = (int)(kk & 0x3FFFFu);
        int cr  = (int)(kk >> 18);
        unsigned int hpu = hp2[(size_t)sub * 32 + li];
        unsigned int cvu = ct2[(size_t)cr * 32 + li];
        float2 hd = hidden2[(size_t)sub * 32 + li];
        float2 rl = rela2[(size_t)(cr >> 3) * 32 + li];

        for (int j = s + 2; j < e; j += 2) {
            int j1n = min(j + 1, e - 1);
            unsigned int ka1 = key[j], kb1 = key[j1n];
            unsigned int kk1 = half ? kb1 : ka1;
            float vld1 = (half == 0 || j + 1 < e) ? 1.f : 0.f;
            int sub1 = (int)(kk1 & 0x3FFFFu);
            int cr1  = (int)(kk1 >> 18);
            unsigned int hpu1 = hp2[(size_t)sub1 * 32 + li];
            unsigned int cvu1 = ct2[(size_t)cr1 * 32 + li];
            float2 hd1 = hidden2[(size_t)sub1 * 32 + li];
            float2 rl1 = rela2[(size_t)(cr1 >> 3) * 32 + li];

            float hpx = __uint_as_float(hpu << 16);
            float hpy = __uint_as_float(hpu & 0xFFFF0000u);
            float cvx = __uint_as_float(cvu << 16);
            float cvy = __uint_as_float(cvu & 0xFFFF0000u);
            float tt = fmaxf(hpx + cvx, 0.f) * wav.x
                     + fmaxf(hpy + cvy, 0.f) * wav.y;
#pragma unroll
            for (int o = 16; o; o >>= 1) tt += __shfl_xor(tt, o, 64);
            float am = vld / (1.f + __expf(-(tt + wab)));
            acc.x += am * (hd.x + rl.x);
            acc.y += am * (hd.y + rl.y);
            hpu = hpu1; cvu = cvu1; hd = hd1; rl = rl1; vld = vld1;
        }
        float hpx = __uint_as_float(hpu << 16);
        float hpy = __uint_as_float(hpu & 0xFFFF0000u);
        float cvx = __uint_as_float(cvu << 16);
        float cvy = __uint_as_float(cvu & 0xFFFF0000u);
        float tt = fmaxf(hpx + cvx, 0.f) * wav.x
                 + fmaxf(hpy + cvy, 0.f) * wav.y;
#pragma unroll
        for (int o = 16; o; o >>= 1) tt += __shfl_xor(tt, o, 64);
        float am = vld / (1.f + __expf(-(tt + wab)));
        acc.x += am * (hd.x + rl.x);
        acc.y += am * (hd.y + rl.y);
    }
    acc.x += __shfl_xor(acc.x, 32, 64);
    acc.y += __shfl_xor(acc.y, 32, 64);
    if (half == 0) ((float2*)agg)[(size_t)n * 32 + li] = acc;
}

extern "C" void kernel_launch(void* const* d_in, const int* in_sizes, int n_in,
                              void* d_out, int out_size, void* d_ws, size_t ws_size,
                              hipStream_t stream) {
    const int* q_rel    = (const int*)d_in[1];
    const float* hidden = (const float*)d_in[2];
    const int* edges    = (const int*)d_in[3];
    const float* rela   = (const float*)d_in[7];
    const float* Ws     = (const float*)d_in[8];
    const float* Wr     = (const float*)d_in[9];
    const float* WqrW   = (const float*)d_in[10];
    const float* Wqrb   = (const float*)d_in[11];
    const float* waW    = (const float*)d_in[12];
    const float* wab    = (const float*)d_in[13];
    const float* Wh     = (const float*)d_in[14];

    int E = in_sizes[3] / 6;            // 1,000,000
    int n_node = in_sizes[4] / 2;       // 200,000
    int n_rel_tot = in_sizes[7] / 64;   // 401
    int B = in_sizes[0];                // 8 (k_ct assumes <= 8)

    float* agg = (float*)d_out;                          // n_node*64
    char* w = (char*)d_ws;
    unsigned short* hproj16 = (unsigned short*)w;  w += (size_t)n_node * 64 * 2;
    unsigned short* ct16    = (unsigned short*)w;  w += (size_t)n_rel_tot * 8 * 64 * 2;
    unsigned int* key = (unsigned int*)w;          w += (size_t)E * 4;
    int* rank    = (int*)w;                        w += (size_t)E * 4;
    int* deg     = (int*)w;                        w += (size_t)n_node * 4;
    int* rowptr  = (int*)w;                        w += (size_t)(n_node + 1) * 4;
    int* partial = (int*)w;                        w += 512 * 4;
    int* poffs   = (int*)w;                        w += 512 * 4;

    // 1-2: projection tables (bf16)
    rowproj_bf16<<<n_node / 64, 256, 0, stream>>>(hidden, Ws, hproj16, n_node);
    k_ct<<<n_rel_tot, 64, 0, stream>>>(rela, q_rel, Wr, WqrW, Wqrb, ct16, B);

    // 3: cooperative CSR build + key scatter (one dispatch)
    void* args[] = {(void*)&edges, (void*)&E, (void*)&n_node,
                    (void*)&deg, (void*)&rank, (void*)&partial,
                    (void*)&poffs, (void*)&rowptr, (void*)&key};
    hipLaunchCooperativeKernel((const void*)k_csr, dim3(512), dim3(256),
                               args, 0, stream);

    // 4-5: fused alpha+aggregate, then out-projection in place
    k_agg<<<(n_node * 64 + 255) / 256, 256, 0, stream>>>(
        rowptr, key, hproj16, ct16, hidden, rela, waW, wab, agg, n_node);
    rowproj64<<<n_node / 64, 256, 0, stream>>>(agg, Wh, agg, n_node);
}

// Round 15
// 393.127 us; speedup vs baseline: 1.7174x; 1.7174x over previous
//
#include <hip/hip_runtime.h>
#include <hip/hip_bf16.h>

// ---------------------------------------------------------------------------
// GNN layer (R15 = R12 resubmit): split CSR (R10) + bf16 tables (R11) +
// 4-edges-per-wave k_agg (new lever, unmeasured).
//   1. rowproj_bf16: hproj16 = bf16(hidden @ Ws^T); also zeros deg
//   2. k_ct:         ct16[rel*8+b] = bf16(rela@Wr^T + rela[q_rel[b]]@Wqr^T+b)
//   3. k_count: deg/rank   4-6. scan -> rowptr   7. k_key (atomic-free)
//   8. k_agg: wave = 4 edges x 16 lanes x float4; gathers hp/cv bf16, hd/rl
//      fp32; one exp + 4 shuffles serve 4 edges; 1 store/node
//   9. rowproj64: out = agg @ Wh^T in place on d_out
// R11 evidence: cooperative grid.sync = 320us of barrier spin (REVERTED);
// fixed ~150-200us harness overhead regardless of dispatch count.
// ---------------------------------------------------------------------------

__device__ __forceinline__ unsigned short f2bf(float f) {
    unsigned int u = __float_as_uint(f);
    u += 0x7FFF + ((u >> 16) & 1);          // round-to-nearest-even
    return (unsigned short)(u >> 16);
}

// dst[r][a] = sum_k src[r][k] * W[a][k];  fp32 in/out, used in-place for the
// final projection (rows staged in LDS before overwrite).
__global__ __launch_bounds__(256) void rowproj64(const float* src,
                                                 const float* __restrict__ W,
                                                 float* dst, int nrows) {
    __shared__ float Wt[64][65];
    __shared__ float4 Sl[64][16];
    int tid = threadIdx.x;
    for (int i = tid; i < 4096; i += 256) Wt[i & 63][i >> 6] = W[i];
    long r0 = (long)blockIdx.x * 64;
    const float4* src4 = (const float4*)(src + r0 * 64);
    float4* s4 = (float4*)Sl;
    for (int i = tid; i < 1024; i += 256) s4[i] = src4[i];
    __syncthreads();
    int c = tid & 63;
    int rbase = (tid >> 6) * 16;
    float w[64];
#pragma unroll
    for (int k = 0; k < 64; ++k) w[k] = Wt[k][c];
#pragma unroll
    for (int r = 0; r < 16; ++r) {
        float a0 = 0.f, a1 = 0.f, a2 = 0.f, a3 = 0.f;
#pragma unroll
        for (int k4 = 0; k4 < 16; ++k4) {
            float4 s = Sl[rbase + r][k4];
            a0 += s.x * w[4 * k4 + 0];
            a1 += s.y * w[4 * k4 + 1];
            a2 += s.z * w[4 * k4 + 2];
            a3 += s.w * w[4 * k4 + 3];
        }
        dst[(r0 + rbase + r) * 64 + c] = (a0 + a1) + (a2 + a3);
    }
}

// Same projection, bf16 output; also zeroes deg (runs before k_count in
// stream order, replacing the memset dispatch).
__global__ __launch_bounds__(256) void rowproj_bf16(const float* __restrict__ src,
                                                    const float* __restrict__ W,
                                                    unsigned short* __restrict__ dst,
                                                    int* __restrict__ deg,
                                                    int nrows) {
    __shared__ float Wt[64][65];
    __shared__ float4 Sl[64][16];
    int tid = threadIdx.x;
    long r0 = (long)blockIdx.x * 64;
    if (tid < 64 && r0 + tid < nrows) deg[r0 + tid] = 0;
    for (int i = tid; i < 4096; i += 256) Wt[i & 63][i >> 6] = W[i];
    const float4* src4 = (const float4*)(src + r0 * 64);
    float4* s4 = (float4*)Sl;
    for (int i = tid; i < 1024; i += 256) s4[i] = src4[i];
    __syncthreads();
    int c = tid & 63;
    int rbase = (tid >> 6) * 16;
    float w[64];
#pragma unroll
    for (int k = 0; k < 64; ++k) w[k] = Wt[k][c];
#pragma unroll
    for (int r = 0; r < 16; ++r) {
        float a0 = 0.f, a1 = 0.f, a2 = 0.f, a3 = 0.f;
#pragma unroll
        for (int k4 = 0; k4 < 16; ++k4) {
            float4 s = Sl[rbase + r][k4];
            a0 += s.x * w[4 * k4 + 0];
            a1 += s.y * w[4 * k4 + 1];
            a2 += s.z * w[4 * k4 + 2];
            a3 += s.w * w[4 * k4 + 3];
        }
        dst[(r0 + rbase + r) * 64 + c] = f2bf((a0 + a1) + (a2 + a3));
    }
}

// ct16[rel*8+b][a] = bf16((rela[rel]@Wr^T)[a] + (rela[q_rel[b]]@Wqr^T)[a] + bqr[a])
__global__ void k_ct(const float* __restrict__ rela,
                     const int* __restrict__ q_rel,
                     const float* __restrict__ Wr,
                     const float* __restrict__ Wqr,
                     const float* __restrict__ bqr,
                     unsigned short* __restrict__ ct, int B) {
    int rel = blockIdx.x, a = threadIdx.x;
    __shared__ float hr[64];
    __shared__ float hq[8][64];
    hr[a] = rela[(size_t)rel * 64 + a];
    for (int b = 0; b < B; ++b) hq[b][a] = rela[(size_t)q_rel[b] * 64 + a];
    __syncthreads();
    float accr = 0.f;
#pragma unroll
    for (int k = 0; k < 64; ++k) accr += hr[k] * Wr[a * 64 + k];
    for (int b = 0; b < B; ++b) {
        float acc = bqr[a];
#pragma unroll
        for (int k = 0; k < 64; ++k) acc += hq[b][k] * Wqr[a * 64 + k];
        ct[((size_t)rel * 8 + b) * 64 + a] = f2bf(accr + acc);
    }
}

// ---- CSR build (split kernels, proven R10) ---------------------------------
__global__ void k_count(const int* __restrict__ edges, int E,
                        int* __restrict__ deg, int* __restrict__ rank) {
    int e = blockIdx.x * blockDim.x + threadIdx.x;
    if (e < E) rank[e] = atomicAdd(&deg[edges[(size_t)e * 6 + 5]], 1);
}

#define SCAN_BS 256
__global__ __launch_bounds__(SCAN_BS) void k_scan_block(
    const int* __restrict__ deg, int N,
    int* __restrict__ rowptr, int* __restrict__ bsum) {
    __shared__ int sh[SCAN_BS];
    int t = threadIdx.x, b = blockIdx.x;
    int base = b * 1024 + t * 4;
    int d0 = (base + 0 < N) ? deg[base + 0] : 0;
    int d1 = (base + 1 < N) ? deg[base + 1] : 0;
    int d2 = (base + 2 < N) ? deg[base + 2] : 0;
    int d3 = (base + 3 < N) ? deg[base + 3] : 0;
    int s = d0 + d1 + d2 + d3;
    sh[t] = s;
    __syncthreads();
    for (int o = 1; o < SCAN_BS; o <<= 1) {
        int v = (t >= o) ? sh[t - o] : 0;
        __syncthreads();
        sh[t] += v;
        __syncthreads();
    }
    int run = sh[t] - s;  // exclusive
    if (t == SCAN_BS - 1) bsum[b] = sh[t];
    if (base + 0 < N) rowptr[base + 0] = run;  run += d0;
    if (base + 1 < N) rowptr[base + 1] = run;  run += d1;
    if (base + 2 < N) rowptr[base + 2] = run;  run += d2;
    if (base + 3 < N) rowptr[base + 3] = run;
}

__global__ __launch_bounds__(SCAN_BS) void k_scan_partials(
    const int* __restrict__ bsum, int* __restrict__ boffs, int NB) {
    __shared__ int sh[SCAN_BS];
    int t = threadIdx.x;
    int v = (t < NB) ? bsum[t] : 0;
    sh[t] = v;
    __syncthreads();
    for (int o = 1; o < SCAN_BS; o <<= 1) {
        int u = (t >= o) ? sh[t - o] : 0;
        __syncthreads();
        sh[t] += u;
        __syncthreads();
    }
    if (t < NB) boffs[t] = sh[t] - v;
}

__global__ void k_add_offsets(int* __restrict__ rowptr,
                              const int* __restrict__ boffs, int N, int E) {
    int i = blockIdx.x * blockDim.x + threadIdx.x;
    if (i < N) rowptr[i] += boffs[i >> 10];
    if (i == 0) rowptr[N] = E;
}

__global__ void k_key(const int* __restrict__ edges, int E,
                      const int* __restrict__ rowptr,
                      const int* __restrict__ rank,
                      unsigned int* __restrict__ key) {
    int e = blockIdx.x * blockDim.x + threadIdx.x;
    if (e >= E) return;
    const int* ed = edges + (size_t)e * 6;
    int r_idx = ed[0], rel = ed[2], sub = ed[4], obj = ed[5];
    int pos = rowptr[obj] + rank[e];
    key[pos] = (unsigned int)sub | ((unsigned int)(rel * 8 + r_idx) << 18);
}

// ---- FUSED alpha + aggregation, 4 edges per wave ---------------------------
// lane = g*16+li: group g (0..3) owns edge j+g, lane li owns features
// {4li..4li+3}. One gather instruction per table serves 4 edges; 4 shuffles
// reduce all 4 dots; one exp serves 4 sigmoids. 2-deep pipeline.
__global__ __launch_bounds__(256) void k_agg(
    const int* __restrict__ rowptr,
    const unsigned int* __restrict__ key,
    const unsigned short* __restrict__ hproj16,
    const unsigned short* __restrict__ ct16,
    const float* __restrict__ hidden,
    const float* __restrict__ rela,
    const float* __restrict__ wa,
    const float* __restrict__ wab_p,
    float* __restrict__ agg, int N) {
    int lane = threadIdx.x & 63;
    int g  = lane >> 4;
    int li = lane & 15;
    int w = (int)((blockIdx.x * blockDim.x + threadIdx.x) >> 6);
    if (w >= N) return;
    int n = __builtin_amdgcn_readfirstlane(w);
    int s = rowptr[n], e = rowptr[n + 1];
    const uint2* hp2 = (const uint2*)hproj16;   // 16 x 8B per row
    const uint2* ct2 = (const uint2*)ct16;
    const float4* hidden4 = (const float4*)hidden;
    const float4* rela4   = (const float4*)rela;
    float4 wav = ((const float4*)wa)[li];
    float wab = wab_p[0];
    float4 acc = {0.f, 0.f, 0.f, 0.f};

#define LOADK(J, KK, VLD, SUB, CR, HPU, CVU, HD, RL)                          \
    {                                                                         \
        int j1 = min((J) + 1, e - 1), j2 = min((J) + 2, e - 1),               \
            j3 = min((J) + 3, e - 1);                                         \
        unsigned int k0 = key[(J)], k1 = key[j1], k2 = key[j2], k3 = key[j3]; \
        unsigned int ka = (g & 1) ? k1 : k0, kb = (g & 1) ? k3 : k2;          \
        KK = (g & 2) ? kb : ka;                                               \
        VLD = ((J) + g < e) ? 1.f : 0.f;                                      \
        SUB = (int)(KK & 0x3FFFFu);                                           \
        CR = (int)(KK >> 18);                                                 \
        HPU = hp2[(size_t)SUB * 16 + li];                                     \
        CVU = ct2[(size_t)CR * 16 + li];                                      \
        HD = hidden4[(size_t)SUB * 16 + li];                                  \
        RL = rela4[(size_t)(CR >> 3) * 16 + li];                              \
    }

#define CONSUME(VLD, HPU, CVU, HD, RL)                                        \
    {                                                                         \
        float h0 = __uint_as_float(HPU.x << 16);                              \
        float h1 = __uint_as_float(HPU.x & 0xFFFF0000u);                      \
        float h2 = __uint_as_float(HPU.y << 16);                              \
        float h3 = __uint_as_float(HPU.y & 0xFFFF0000u);                      \
        float c0 = __uint_as_float(CVU.x << 16);                              \
        float c1 = __uint_as_float(CVU.x & 0xFFFF0000u);                      \
        float c2 = __uint_as_float(CVU.y << 16);                              \
        float c3 = __uint_as_float(CVU.y & 0xFFFF0000u);                      \
        float tt = fmaxf(h0 + c0, 0.f) * wav.x + fmaxf(h1 + c1, 0.f) * wav.y  \
                 + fmaxf(h2 + c2, 0.f) * wav.z + fmaxf(h3 + c3, 0.f) * wav.w; \
        tt += __shfl_xor(tt, 8, 64);                                          \
        tt += __shfl_xor(tt, 4, 64);                                          \
        tt += __shfl_xor(tt, 2, 64);                                          \
        tt += __shfl_xor(tt, 1, 64);                                          \
        float am = VLD / (1.f + __expf(-(tt + wab)));                         \
        acc.x += am * (HD.x + RL.x);                                          \
        acc.y += am * (HD.y + RL.y);                                          \
        acc.z += am * (HD.z + RL.z);                                          \
        acc.w += am * (HD.w + RL.w);                                          \
    }

    if (s < e) {
        unsigned int kk; float vld; int sub, cr;
        uint2 hpu, cvu; float4 hd, rl;
        LOADK(s, kk, vld, sub, cr, hpu, cvu, hd, rl);
        for (int j = s + 4; j < e; j += 4) {
            unsigned int kk1; float vld1; int sub1, cr1;
            uint2 hpu1, cvu1; float4 hd1, rl1;
            LOADK(j, kk1, vld1, sub1, cr1, hpu1, cvu1, hd1, rl1);
            CONSUME(vld, hpu, cvu, hd, rl);
            hpu = hpu1; cvu = cvu1; hd = hd1; rl = rl1; vld = vld1;
        }
        CONSUME(vld, hpu, cvu, hd, rl);
    }
    // sum the 4 groups' partial accumulators
    acc.x += __shfl_xor(acc.x, 16, 64);  acc.x += __shfl_xor(acc.x, 32, 64);
    acc.y += __shfl_xor(acc.y, 16, 64);  acc.y += __shfl_xor(acc.y, 32, 64);
    acc.z += __shfl_xor(acc.z, 16, 64);  acc.z += __shfl_xor(acc.z, 32, 64);
    acc.w += __shfl_xor(acc.w, 16, 64);  acc.w += __shfl_xor(acc.w, 32, 64);
    if (g == 0) ((float4*)agg)[(size_t)n * 16 + li] = acc;
#undef LOADK
#undef CONSUME
}

extern "C" void kernel_launch(void* const* d_in, const int* in_sizes, int n_in,
                              void* d_out, int out_size, void* d_ws, size_t ws_size,
                              hipStream_t stream) {
    const int* q_rel    = (const int*)d_in[1];
    const float* hidden = (const float*)d_in[2];
    const int* edges    = (const int*)d_in[3];
    const float* rela   = (const float*)d_in[7];
    const float* Ws     = (const float*)d_in[8];
    const float* Wr     = (const float*)d_in[9];
    const float* WqrW   = (const float*)d_in[10];
    const float* Wqrb   = (const float*)d_in[11];
    const float* waW    = (const float*)d_in[12];
    const float* wab    = (const float*)d_in[13];
    const float* Wh     = (const float*)d_in[14];

    int E = in_sizes[3] / 6;            // 1,000,000
    int n_node = in_sizes[4] / 2;       // 200,000
    int n_rel_tot = in_sizes[7] / 64;   // 401
    int B = in_sizes[0];                // 8 (k_ct assumes <= 8)
    int NB = (n_node + 1023) / 1024;    // scan blocks (196 <= 256)

    float* agg = (float*)d_out;                          // n_node*64
    char* w = (char*)d_ws;
    unsigned short* hproj16 = (unsigned short*)w;  w += (size_t)n_node * 64 * 2;
    unsigned short* ct16    = (unsigned short*)w;  w += (size_t)n_rel_tot * 8 * 64 * 2;
    unsigned int* key = (unsigned int*)w;          w += (size_t)E * 4;
    int* rank   = (int*)w;                         w += (size_t)E * 4;
    int* deg    = (int*)w;                         w += (size_t)n_node * 4;
    int* rowptr = (int*)w;                         w += (size_t)(n_node + 1) * 4;
    int* bsum   = (int*)w;                         w += (size_t)NB * 4;
    int* boffs  = (int*)w;                         w += (size_t)NB * 4;

    // projection tables (bf16); rowproj_bf16 also zeroes deg
    rowproj_bf16<<<n_node / 64, 256, 0, stream>>>(hidden, Ws, hproj16, deg, n_node);
    k_ct<<<n_rel_tot, 64, 0, stream>>>(rela, q_rel, Wr, WqrW, Wqrb, ct16, B);

    // CSR build (rank captured during count; atomic-free key)
    k_count<<<(E + 255) / 256, 256, 0, stream>>>(edges, E, deg, rank);
    k_scan_block<<<NB, SCAN_BS, 0, stream>>>(deg, n_node, rowptr, bsum);
    k_scan_partials<<<1, SCAN_BS, 0, stream>>>(bsum, boffs, NB);
    k_add_offsets<<<(n_node + 255) / 256, 256, 0, stream>>>(rowptr, boffs,
                                                            n_node, E);
    k_key<<<(E + 255) / 256, 256, 0, stream>>>(edges, E, rowptr, rank, key);

    // fused alpha+aggregate (4 edges/wave), then out-projection in place
    k_agg<<<(n_node * 64 + 255) / 256, 256, 0, stream>>>(
        rowptr, key, hproj16, ct16, hidden, rela, waW, wab, agg, n_node);
    rowproj64<<<n_node / 64, 256, 0, stream>>>(agg, Wh, agg, n_node);
}